// Round 2
// baseline (1413.484 us; speedup 1.0000x reference)
//
#include <hip/hip_runtime.h>
#include <math.h>

#define S_ORIG 4095
#define LPAD   4096
#define NHEADS 16
#define DH     64
#define NLM    128
#define BHT    32        // B * NHEADS
#define HIDDEN 1024
#define QKSCALE 0.35355339059327373f   // 1 / 64^0.25

// ---------------------------------------------------------------------------
// Transpose 1024x1024 weight:  Wt[k][c] = W[c][k]
// ---------------------------------------------------------------------------
__global__ __launch_bounds__(256) void k_transpose(const float* __restrict__ W,
                                                   float* __restrict__ Wt) {
    __shared__ float t[32][33];
    int tx = threadIdx.x, ty = threadIdx.y;          // 32 x 8
    int k0 = blockIdx.x * 32, c0 = blockIdx.y * 32;
    #pragma unroll
    for (int i = 0; i < 32; i += 8)
        t[ty + i][tx] = W[(size_t)(c0 + ty + i) * HIDDEN + k0 + tx];
    __syncthreads();
    #pragma unroll
    for (int i = 0; i < 32; i += 8)
        Wt[(size_t)(k0 + ty + i) * HIDDEN + c0 + tx] = t[tx][ty + i];
}

// ---------------------------------------------------------------------------
// Projection GEMM: Y = A @ Wt + bias.   A is logical (2*4096) x 1024.
// mode 0: A = X (B,4095,H) with implicit zero pad row l==4095;
//         out layout [b][h][l][d]; if mask != nullptr multiply by mask[gr]*QKSCALE.
// mode 1: A = ATTN (B*L, H); out = d_out, only rows l < 4095 stored.
// 128x128 tile, BK=16, 256 threads, 8x8 per thread.
// ---------------------------------------------------------------------------
__global__ __launch_bounds__(256) void k_proj(const float* __restrict__ A,
                                              const float* __restrict__ Wt,
                                              const float* __restrict__ bias,
                                              const float* __restrict__ mask,
                                              float* __restrict__ out,
                                              int mode) {
    __shared__ float As[16][132];
    __shared__ float Bs[16][132];
    int tid = threadIdx.x;
    int tx = tid & 15, ty = tid >> 4;
    int row0 = blockIdx.x * 128, col0 = blockIdx.y * 128;
    int ar = tid >> 2, akq = tid & 3;
    int bkk = tid >> 5, bc4 = tid & 31;

    float acc[8][8];
    #pragma unroll
    for (int i = 0; i < 8; ++i)
        #pragma unroll
        for (int j = 0; j < 8; ++j) acc[i][j] = 0.f;

    for (int kt = 0; kt < HIDDEN; kt += 16) {
        #pragma unroll
        for (int h = 0; h < 2; ++h) {
            int r = ar + h * 64;
            int gr = row0 + r;
            int b = gr >> 12, l = gr & (LPAD - 1);
            float4 v = make_float4(0.f, 0.f, 0.f, 0.f);
            if (mode == 1) {
                v = *(const float4*)(A + (size_t)gr * HIDDEN + kt + akq * 4);
            } else if (l < S_ORIG) {
                v = *(const float4*)(A + ((size_t)b * S_ORIG + l) * HIDDEN + kt + akq * 4);
            }
            As[akq * 4 + 0][r] = v.x; As[akq * 4 + 1][r] = v.y;
            As[akq * 4 + 2][r] = v.z; As[akq * 4 + 3][r] = v.w;
        }
        #pragma unroll
        for (int h = 0; h < 2; ++h) {
            int kk = bkk + h * 8;
            float4 v = *(const float4*)(Wt + (size_t)(kt + kk) * HIDDEN + col0 + bc4 * 4);
            *(float4*)&Bs[kk][bc4 * 4] = v;
        }
        __syncthreads();
        #pragma unroll
        for (int k = 0; k < 16; ++k) {
            float av[8], bv[8];
            float4 t0 = *(const float4*)&As[k][ty * 4];
            float4 t1 = *(const float4*)&As[k][64 + ty * 4];
            float4 t2 = *(const float4*)&Bs[k][tx * 4];
            float4 t3 = *(const float4*)&Bs[k][64 + tx * 4];
            av[0]=t0.x; av[1]=t0.y; av[2]=t0.z; av[3]=t0.w;
            av[4]=t1.x; av[5]=t1.y; av[6]=t1.z; av[7]=t1.w;
            bv[0]=t2.x; bv[1]=t2.y; bv[2]=t2.z; bv[3]=t2.w;
            bv[4]=t3.x; bv[5]=t3.y; bv[6]=t3.z; bv[7]=t3.w;
            #pragma unroll
            for (int i = 0; i < 8; ++i)
                #pragma unroll
                for (int j = 0; j < 8; ++j)
                    acc[i][j] = fmaf(av[i], bv[j], acc[i][j]);
        }
        __syncthreads();
    }

    #pragma unroll
    for (int i = 0; i < 8; ++i) {
        int gr = row0 + (i >> 2) * 64 + ty * 4 + (i & 3);
        int b = gr >> 12, l = gr & (LPAD - 1);
        #pragma unroll
        for (int jh = 0; jh < 2; ++jh) {
            int c = col0 + jh * 64 + tx * 4;
            float4 bias4 = *(const float4*)(bias + c);
            float4 res;
            res.x = acc[i][jh * 4 + 0] + bias4.x;
            res.y = acc[i][jh * 4 + 1] + bias4.y;
            res.z = acc[i][jh * 4 + 2] + bias4.z;
            res.w = acc[i][jh * 4 + 3] + bias4.w;
            if (mode == 0) {
                if (mask) {
                    float sc = mask[gr] * QKSCALE;
                    res.x *= sc; res.y *= sc; res.z *= sc; res.w *= sc;
                }
                int hh = c >> 6, d = c & 63;
                *(float4*)(out + (((size_t)b * NHEADS + hh) * LPAD + l) * DH + d) = res;
            } else {
                if (l < S_ORIG)
                    *(float4*)(out + ((size_t)b * S_ORIG + l) * HIDDEN + c) = res;
            }
        }
    }
}

// ---------------------------------------------------------------------------
// Landmarks: mean over 32 consecutive rows of Q and K. grid (128, 32), 64 thr.
// ---------------------------------------------------------------------------
__global__ void k_landmarks(const float* __restrict__ Q, const float* __restrict__ K,
                            float* __restrict__ QL, float* __restrict__ KL) {
    int n = blockIdx.x, bh = blockIdx.y, d = threadIdx.x;
    size_t base = ((size_t)bh * LPAD + n * 32) * DH + d;
    float sq = 0.f, sk = 0.f;
    #pragma unroll
    for (int s = 0; s < 32; ++s) {
        sq += Q[base + (size_t)s * DH];
        sk += K[base + (size_t)s * DH];
    }
    QL[((size_t)bh * NLM + n) * DH + d] = sq * (1.f / 32.f);
    KL[((size_t)bh * NLM + n) * DH + d] = sk * (1.f / 32.f);
}

// ---------------------------------------------------------------------------
// S = QL @ B^T  (128 x 128, inner 64).
// mode 0: B = KL (128 rows), row-softmax, out K2 (ld 128).
// mode 1: B = K tile (128 rows at n0), out raw scores - 1e9*(1-mask) (ld 4096).
// ---------------------------------------------------------------------------
__global__ __launch_bounds__(256) void k_qlk(const float* __restrict__ QLb,
                                             const float* __restrict__ Bsrc,
                                             const float* __restrict__ mask,
                                             float* __restrict__ out,
                                             int ld_out, int mode) {
    __shared__ float Qt[64][132];
    __shared__ float Bt[64][132];
    int tid = threadIdx.x;
    int tx = tid & 15, ty = tid >> 4;
    int bh = blockIdx.y;
    int n0 = blockIdx.x * 128;
    const float* QLp = QLb + (size_t)bh * NLM * DH;
    const float* Bp = Bsrc + ((mode == 0) ? (size_t)bh * NLM * DH
                                          : (size_t)bh * LPAD * DH + (size_t)n0 * DH);

    #pragma unroll
    for (int q = 0; q < 8; ++q) {
        int idx = tid + q * 256;
        int r = idx >> 4, d4 = idx & 15;
        float4 v = *(const float4*)(QLp + (size_t)r * DH + d4 * 4);
        Qt[d4 * 4 + 0][r] = v.x; Qt[d4 * 4 + 1][r] = v.y;
        Qt[d4 * 4 + 2][r] = v.z; Qt[d4 * 4 + 3][r] = v.w;
        float4 w = *(const float4*)(Bp + (size_t)r * DH + d4 * 4);
        Bt[d4 * 4 + 0][r] = w.x; Bt[d4 * 4 + 1][r] = w.y;
        Bt[d4 * 4 + 2][r] = w.z; Bt[d4 * 4 + 3][r] = w.w;
    }
    __syncthreads();

    float acc[8][8];
    #pragma unroll
    for (int i = 0; i < 8; ++i)
        #pragma unroll
        for (int j = 0; j < 8; ++j) acc[i][j] = 0.f;

    #pragma unroll
    for (int k = 0; k < 64; ++k) {
        float av[8], bv[8];
        float4 t0 = *(const float4*)&Qt[k][ty * 4];
        float4 t1 = *(const float4*)&Qt[k][64 + ty * 4];
        float4 t2 = *(const float4*)&Bt[k][tx * 4];
        float4 t3 = *(const float4*)&Bt[k][64 + tx * 4];
        av[0]=t0.x; av[1]=t0.y; av[2]=t0.z; av[3]=t0.w;
        av[4]=t1.x; av[5]=t1.y; av[6]=t1.z; av[7]=t1.w;
        bv[0]=t2.x; bv[1]=t2.y; bv[2]=t2.z; bv[3]=t2.w;
        bv[4]=t3.x; bv[5]=t3.y; bv[6]=t3.z; bv[7]=t3.w;
        #pragma unroll
        for (int i = 0; i < 8; ++i)
            #pragma unroll
            for (int j = 0; j < 8; ++j)
                acc[i][j] = fmaf(av[i], bv[j], acc[i][j]);
    }

    if (mode == 1) {
        int b = bh >> 4;
        #pragma unroll
        for (int i = 0; i < 8; ++i) {
            int r = (i >> 2) * 64 + ty * 4 + (i & 3);
            #pragma unroll
            for (int jh = 0; jh < 2; ++jh) {
                int c = n0 + jh * 64 + tx * 4;
                float4 m4 = *(const float4*)(mask + (size_t)b * LPAD + c);
                float4 res;
                res.x = acc[i][jh * 4 + 0] - 1e9f * (1.f - m4.x);
                res.y = acc[i][jh * 4 + 1] - 1e9f * (1.f - m4.y);
                res.z = acc[i][jh * 4 + 2] - 1e9f * (1.f - m4.z);
                res.w = acc[i][jh * 4 + 3] - 1e9f * (1.f - m4.w);
                *(float4*)(out + ((size_t)bh * NLM + r) * ld_out + c) = res;
            }
        }
    } else {
        float m[8], s[8];
        #pragma unroll
        for (int i = 0; i < 8; ++i) {
            m[i] = acc[i][0];
            #pragma unroll
            for (int j = 1; j < 8; ++j) m[i] = fmaxf(m[i], acc[i][j]);
        }
        #pragma unroll
        for (int o = 8; o >= 1; o >>= 1)
            #pragma unroll
            for (int i = 0; i < 8; ++i) m[i] = fmaxf(m[i], __shfl_xor(m[i], o));
        #pragma unroll
        for (int i = 0; i < 8; ++i) {
            s[i] = 0.f;
            #pragma unroll
            for (int j = 0; j < 8; ++j) {
                acc[i][j] = expf(acc[i][j] - m[i]);
                s[i] += acc[i][j];
            }
        }
        #pragma unroll
        for (int o = 8; o >= 1; o >>= 1)
            #pragma unroll
            for (int i = 0; i < 8; ++i) s[i] += __shfl_xor(s[i], o);
        #pragma unroll
        for (int i = 0; i < 8; ++i) {
            int r = (i >> 2) * 64 + ty * 4 + (i & 3);
            float inv = 1.f / s[i];
            #pragma unroll
            for (int jh = 0; jh < 2; ++jh) {
                int c = jh * 64 + tx * 4;
                float4 res;
                res.x = acc[i][jh * 4 + 0] * inv;
                res.y = acc[i][jh * 4 + 1] * inv;
                res.z = acc[i][jh * 4 + 2] * inv;
                res.w = acc[i][jh * 4 + 3] * inv;
                *(float4*)(out + ((size_t)bh * NLM + r) * ld_out + c) = res;
            }
        }
    }
}

// ---------------------------------------------------------------------------
// denom + V0 = K2^T / denom. grid 32, 128 threads.
// ---------------------------------------------------------------------------
__global__ void k_v0denom(const float* __restrict__ K2b, float* __restrict__ V0b) {
    int bh = blockIdx.x, t = threadIdx.x;
    const float* K2 = K2b + (size_t)bh * NLM * NLM;
    float* V0 = V0b + (size_t)bh * NLM * NLM;
    float cs = 0.f, rs = 0.f;
    for (int r = 0; r < NLM; ++r) cs += fabsf(K2[r * NLM + t]);
    for (int c = 0; c < NLM; ++c) rs += fabsf(K2[t * NLM + c]);
    __shared__ float sc[128], sr[128];
    sc[t] = cs; sr[t] = rs;
    __syncthreads();
    for (int s = 64; s > 0; s >>= 1) {
        if (t < s) {
            sc[t] = fmaxf(sc[t], sc[t + s]);
            sr[t] = fmaxf(sr[t], sr[t + s]);
        }
        __syncthreads();
    }
    float invden = 1.f / (sc[0] * sr[0]);
    for (int idx = t; idx < NLM * NLM; idx += 128) {
        int i = idx >> 7, j = idx & 127;
        V0[idx] = K2[j * NLM + i] * invden;
    }
}

// ---------------------------------------------------------------------------
// Batched matmul: C = alpha*(A@B) + sI  (A 128x128, B 128xN).
// Optional second output C2 = alpha2*(A@B) + s2I.
// grid (N/64, 2, 32), 256 threads, 4x4 per thread, full K=128 staged.
// ---------------------------------------------------------------------------
__global__ __launch_bounds__(256) void k_bmm(const float* __restrict__ Ab,
                                             const float* __restrict__ Bb,
                                             float* __restrict__ Cb,
                                             float* __restrict__ C2b,
                                             int N, float alpha, float sI,
                                             float alpha2, float sI2) {
    __shared__ float At[128][68];
    __shared__ float Bs[128][68];
    int tid = threadIdx.x;
    int tx = tid & 15, ty = tid >> 4;
    int bh = blockIdx.z;
    int r0 = blockIdx.y * 64, c0 = blockIdx.x * 64;
    const float* A = Ab + (size_t)bh * NLM * NLM;
    const float* Bm = Bb + (size_t)bh * NLM * N;

    #pragma unroll
    for (int q = 0; q < 8; ++q) {
        int idx = tid + q * 256;
        int r = idx >> 5, k4 = idx & 31;
        float4 v = *(const float4*)(A + (size_t)(r0 + r) * NLM + k4 * 4);
        At[k4 * 4 + 0][r] = v.x; At[k4 * 4 + 1][r] = v.y;
        At[k4 * 4 + 2][r] = v.z; At[k4 * 4 + 3][r] = v.w;
        int bk = idx >> 4, c4 = idx & 15;
        float4 w = *(const float4*)(Bm + (size_t)bk * N + c0 + c4 * 4);
        *(float4*)&Bs[bk][c4 * 4] = w;
    }
    __syncthreads();

    float acc[4][4];
    #pragma unroll
    for (int i = 0; i < 4; ++i)
        #pragma unroll
        for (int j = 0; j < 4; ++j) acc[i][j] = 0.f;

    #pragma unroll 4
    for (int k = 0; k < 128; ++k) {
        float4 a = *(const float4*)&At[k][ty * 4];
        float4 b = *(const float4*)&Bs[k][tx * 4];
        float av[4] = {a.x, a.y, a.z, a.w};
        float bv[4] = {b.x, b.y, b.z, b.w};
        #pragma unroll
        for (int i = 0; i < 4; ++i)
            #pragma unroll
            for (int j = 0; j < 4; ++j)
                acc[i][j] = fmaf(av[i], bv[j], acc[i][j]);
    }

    float* C = Cb + (size_t)bh * NLM * N;
    float* C2 = C2b ? (C2b + (size_t)bh * NLM * N) : nullptr;
    #pragma unroll
    for (int i = 0; i < 4; ++i) {
        int gr = r0 + ty * 4 + i;
        int gc0 = c0 + tx * 4;
        float4 res, res2;
        float* rp = &res.x; float* rp2 = &res2.x;
        #pragma unroll
        for (int j = 0; j < 4; ++j) {
            float idadd = (gr == gc0 + j) ? 1.f : 0.f;
            rp[j] = alpha * acc[i][j] + sI * idadd;
            rp2[j] = alpha2 * acc[i][j] + sI2 * idadd;
        }
        *(float4*)(C + (size_t)gr * N + gc0) = res;
        if (C2) *(float4*)(C2 + (size_t)gr * N + gc0) = res2;
    }
}

// ---------------------------------------------------------------------------
// Row softmax over 4096-long rows of SC (in place). grid 4096, 256 threads.
// ---------------------------------------------------------------------------
__global__ __launch_bounds__(256) void k_softmax4096(float* __restrict__ SC) {
    float* p = SC + (size_t)blockIdx.x * LPAD;
    int tid = threadIdx.x;
    float4 v[4];
    #pragma unroll
    for (int q = 0; q < 4; ++q) v[q] = *(float4*)(p + tid * 16 + q * 4);

    float m = -1e30f;
    #pragma unroll
    for (int q = 0; q < 4; ++q) {
        m = fmaxf(m, fmaxf(fmaxf(v[q].x, v[q].y), fmaxf(v[q].z, v[q].w)));
    }
    __shared__ float red[4], red2[4];
    for (int o = 32; o >= 1; o >>= 1) m = fmaxf(m, __shfl_xor(m, o));
    int wid = tid >> 6;
    if ((tid & 63) == 0) red[wid] = m;
    __syncthreads();
    m = fmaxf(fmaxf(red[0], red[1]), fmaxf(red[2], red[3]));

    float s = 0.f;
    #pragma unroll
    for (int q = 0; q < 4; ++q) {
        v[q].x = expf(v[q].x - m); v[q].y = expf(v[q].y - m);
        v[q].z = expf(v[q].z - m); v[q].w = expf(v[q].w - m);
        s += v[q].x + v[q].y + v[q].z + v[q].w;
    }
    for (int o = 32; o >= 1; o >>= 1) s += __shfl_xor(s, o);
    if ((tid & 63) == 0) red2[wid] = s;
    __syncthreads();
    s = red2[0] + red2[1] + red2[2] + red2[3];
    float inv = 1.f / s;
    #pragma unroll
    for (int q = 0; q < 4; ++q) {
        v[q].x *= inv; v[q].y *= inv; v[q].z *= inv; v[q].w *= inv;
        *(float4*)(p + tid * 16 + q * 4) = v[q];
    }
}

// ---------------------------------------------------------------------------
// Partial kernel_3 @ V over a 256-wide n chunk. grid (16, 32), 256 threads.
// ---------------------------------------------------------------------------
__global__ __launch_bounds__(256) void k_k3v_partial(const float* __restrict__ SC,
                                                     const float* __restrict__ V,
                                                     float* __restrict__ P) {
    __shared__ float Pt[64][132];
    __shared__ float Vs[64][68];
    int tid = threadIdx.x;
    int tx = tid & 7, ty = tid >> 3;
    int sp = blockIdx.x, bh = blockIdx.y;
    int n0 = sp * 256;

    float acc[4][8];
    #pragma unroll
    for (int i = 0; i < 4; ++i)
        #pragma unroll
        for (int j = 0; j < 8; ++j) acc[i][j] = 0.f;

    for (int ns = 0; ns < 4; ++ns) {
        int nb = n0 + ns * 64;
        #pragma unroll
        for (int q = 0; q < 8; ++q) {
            int idx = tid + q * 256;
            int r = idx >> 4, n4 = idx & 15;
            float4 v = *(const float4*)(SC + ((size_t)bh * NLM + r) * LPAD + nb + n4 * 4);
            Pt[n4 * 4 + 0][r] = v.x; Pt[n4 * 4 + 1][r] = v.y;
            Pt[n4 * 4 + 2][r] = v.z; Pt[n4 * 4 + 3][r] = v.w;
        }
        #pragma unroll
        for (int q = 0; q < 4; ++q) {
            int idx = tid + q * 256;
            int vr = idx >> 4, d4 = idx & 15;
            float4 w = *(const float4*)(V + ((size_t)bh * LPAD + nb + vr) * DH + d4 * 4);
            *(float4*)&Vs[vr][d4 * 4] = w;
        }
        __syncthreads();
        #pragma unroll 4
        for (int nn = 0; nn < 64; ++nn) {
            float4 a4 = *(const float4*)&Pt[nn][ty * 4];
            float4 b0 = *(const float4*)&Vs[nn][tx * 8];
            float4 b1 = *(const float4*)&Vs[nn][tx * 8 + 4];
            float a[4] = {a4.x, a4.y, a4.z, a4.w};
            float b[8] = {b0.x, b0.y, b0.z, b0.w, b1.x, b1.y, b1.z, b1.w};
            #pragma unroll
            for (int i = 0; i < 4; ++i)
                #pragma unroll
                for (int j = 0; j < 8; ++j)
                    acc[i][j] = fmaf(a[i], b[j], acc[i][j]);
        }
        __syncthreads();
    }
    #pragma unroll
    for (int i = 0; i < 4; ++i) {
        int r = ty * 4 + i, d = tx * 8;
        *(float4*)(P + (((size_t)bh * 16 + sp) * NLM + r) * DH + d) =
            make_float4(acc[i][0], acc[i][1], acc[i][2], acc[i][3]);
        *(float4*)(P + (((size_t)bh * 16 + sp) * NLM + r) * DH + d + 4) =
            make_float4(acc[i][4], acc[i][5], acc[i][6], acc[i][7]);
    }
}

__global__ void k_k3v_combine(const float* __restrict__ P, float* __restrict__ O) {
    int idx = blockIdx.x * 256 + threadIdx.x;
    int bh = idx >> 13, rem = idx & 8191;
    float s = 0.f;
    for (int sp = 0; sp < 16; ++sp)
        s += P[((size_t)bh * 16 + sp) * 8192 + rem];
    O[idx] = s;
}

// ---------------------------------------------------------------------------
// kernel_1 stage fused: softmax(Q_tile @ KL^T) @ M  -> ATTN[b][l][h*64+d]
// grid (32 l-tiles, 32 bh), 256 threads. LDS: Qt|KLt reused as P; Ms separate.
// ---------------------------------------------------------------------------
__global__ __launch_bounds__(256) void k_attn(const float* __restrict__ Q,
                                              const float* __restrict__ KLb,
                                              const float* __restrict__ MMb,
                                              float* __restrict__ ATTN) {
    __shared__ float buf[2 * 64 * 132];     // Qt(64x132) | KLt(64x132); later P(128x132)
    __shared__ float Ms[128 * 68];
    int tid = threadIdx.x;
    int tx = tid & 15, ty = tid >> 4;
    int l0 = blockIdx.x * 128, bh = blockIdx.y;
    int b = bh >> 4, hh = bh & 15;
    float* Qt = buf;
    float* KLt = buf + 64 * 132;

    #pragma unroll
    for (int q = 0; q < 8; ++q) {
        int idx = tid + q * 256;
        int r = idx >> 4, d4 = idx & 15;
        float4 v = *(const float4*)(Q + ((size_t)bh * LPAD + l0 + r) * DH + d4 * 4);
        Qt[(d4 * 4 + 0) * 132 + r] = v.x; Qt[(d4 * 4 + 1) * 132 + r] = v.y;
        Qt[(d4 * 4 + 2) * 132 + r] = v.z; Qt[(d4 * 4 + 3) * 132 + r] = v.w;
        float4 w = *(const float4*)(KLb + ((size_t)bh * NLM + r) * DH + d4 * 4);
        KLt[(d4 * 4 + 0) * 132 + r] = w.x; KLt[(d4 * 4 + 1) * 132 + r] = w.y;
        KLt[(d4 * 4 + 2) * 132 + r] = w.z; KLt[(d4 * 4 + 3) * 132 + r] = w.w;
        float4 u = *(const float4*)(MMb + ((size_t)bh * NLM + r) * DH + d4 * 4);
        *(float4*)&Ms[r * 68 + d4 * 4] = u;
    }
    __syncthreads();

    float acc[8][8];
    #pragma unroll
    for (int i = 0; i < 8; ++i)
        #pragma unroll
        for (int j = 0; j < 8; ++j) acc[i][j] = 0.f;

    #pragma unroll
    for (int k = 0; k < 64; ++k) {
        float av[8], bv[8];
        float4 t0 = *(const float4*)&Qt[k * 132 + ty * 4];
        float4 t1 = *(const float4*)&Qt[k * 132 + 64 + ty * 4];
        float4 t2 = *(const float4*)&KLt[k * 132 + tx * 4];
        float4 t3 = *(const float4*)&KLt[k * 132 + 64 + tx * 4];
        av[0]=t0.x; av[1]=t0.y; av[2]=t0.z; av[3]=t0.w;
        av[4]=t1.x; av[5]=t1.y; av[6]=t1.z; av[7]=t1.w;
        bv[0]=t2.x; bv[1]=t2.y; bv[2]=t2.z; bv[3]=t2.w;
        bv[4]=t3.x; bv[5]=t3.y; bv[6]=t3.z; bv[7]=t3.w;
        #pragma unroll
        for (int i = 0; i < 8; ++i)
            #pragma unroll
            for (int j = 0; j < 8; ++j)
                acc[i][j] = fmaf(av[i], bv[j], acc[i][j]);
    }

    // row softmax over 128 cols
    float m[8], s[8];
    #pragma unroll
    for (int i = 0; i < 8; ++i) {
        m[i] = acc[i][0];
        #pragma unroll
        for (int j = 1; j < 8; ++j) m[i] = fmaxf(m[i], acc[i][j]);
    }
    #pragma unroll
    for (int o = 8; o >= 1; o >>= 1)
        #pragma unroll
        for (int i = 0; i < 8; ++i) m[i] = fmaxf(m[i], __shfl_xor(m[i], o));
    #pragma unroll
    for (int i = 0; i < 8; ++i) {
        s[i] = 0.f;
        #pragma unroll
        for (int j = 0; j < 8; ++j) {
            acc[i][j] = expf(acc[i][j] - m[i]);
            s[i] += acc[i][j];
        }
    }
    #pragma unroll
    for (int o = 8; o >= 1; o >>= 1)
        #pragma unroll
        for (int i = 0; i < 8; ++i) s[i] += __shfl_xor(s[i], o);

    __syncthreads();   // all Qt/KLt reads done; safe to overwrite with P
    #pragma unroll
    for (int i = 0; i < 8; ++i) {
        int r = (i >> 2) * 64 + ty * 4 + (i & 3);
        float inv = 1.f / s[i];
        #pragma unroll
        for (int j = 0; j < 8; ++j) {
            int c = (j >> 2) * 64 + tx * 4 + (j & 3);
            buf[r * 132 + c] = acc[i][j] * inv;
        }
    }
    __syncthreads();

    // out = P @ Ms : each thread 8 rows x 4 cols (d = tx*4..)
    float o2[8][4];
    #pragma unroll
    for (int i = 0; i < 8; ++i)
        #pragma unroll
        for (int j = 0; j < 4; ++j) o2[i][j] = 0.f;
    #pragma unroll 4
    for (int n = 0; n < 128; ++n) {
        float4 b4 = *(const float4*)&Ms[n * 68 + tx * 4];
        float bv[4] = {b4.x, b4.y, b4.z, b4.w};
        #pragma unroll
        for (int i = 0; i < 8; ++i) {
            int r = (i >> 2) * 64 + ty * 4 + (i & 3);
            float a = buf[r * 132 + n];
            #pragma unroll
            for (int j = 0; j < 4; ++j)
                o2[i][j] = fmaf(a, bv[j], o2[i][j]);
        }
    }
    #pragma unroll
    for (int i = 0; i < 8; ++i) {
        int l = l0 + (i >> 2) * 64 + ty * 4 + (i & 3);
        *(float4*)(ATTN + ((size_t)b * LPAD + l) * HIDDEN + hh * DH + tx * 4) =
            make_float4(o2[i][0], o2[i][1], o2[i][2], o2[i][3]);
    }
}

// ---------------------------------------------------------------------------
extern "C" void kernel_launch(void* const* d_in, const int* in_sizes, int n_in,
                              void* d_out, int out_size, void* d_ws, size_t ws_size,
                              hipStream_t stream) {
    (void)in_sizes; (void)n_in; (void)out_size; (void)ws_size;
    const float* X    = (const float*)d_in[0];
    const float* mask = (const float*)d_in[1];
    const float* Wq   = (const float*)d_in[2];
    const float* bq   = (const float*)d_in[3];
    const float* Wk   = (const float*)d_in[4];
    const float* bk   = (const float*)d_in[5];
    const float* Wv   = (const float*)d_in[6];
    const float* bv   = (const float*)d_in[7];
    const float* Wo   = (const float*)d_in[8];
    const float* bo   = (const float*)d_in[9];
    float* out = (float*)d_out;
    float* w = (float*)d_ws;

    size_t o = 0;
    float* WTQ = w + o; o += (size_t)HIDDEN * HIDDEN;
    float* WTK = w + o; o += (size_t)HIDDEN * HIDDEN;
    float* WTV = w + o; o += (size_t)HIDDEN * HIDDEN;
    float* WTO = w + o; o += (size_t)HIDDEN * HIDDEN;
    float* Q   = w + o; o += (size_t)BHT * LPAD * DH;
    float* K   = w + o; o += (size_t)BHT * LPAD * DH;
    float* V   = w + o; o += (size_t)BHT * LPAD * DH;
    float* QL  = w + o; o += (size_t)BHT * NLM * DH;
    float* KL  = w + o; o += (size_t)BHT * NLM * DH;
    float* K2  = w + o; o += (size_t)BHT * NLM * NLM;
    float* VA  = w + o; o += (size_t)BHT * NLM * NLM;
    float* VB  = w + o; o += (size_t)BHT * NLM * NLM;
    float* KV  = w + o; o += (size_t)BHT * NLM * NLM;
    float* P1  = w + o; o += (size_t)BHT * NLM * NLM;
    float* T3  = w + o; o += (size_t)BHT * NLM * NLM;
    float* PK  = w + o; o += (size_t)BHT * 16 * NLM * DH;
    float* K3V = w + o; o += (size_t)BHT * NLM * DH;
    float* MM  = w + o; o += (size_t)BHT * NLM * DH;
    float* SC  = w + o; o += (size_t)BHT * NLM * LPAD;
    float* ATTN = SC;   // SC dead before ATTN is written

    dim3 tb(32, 8);
    k_transpose<<<dim3(32, 32), tb, 0, stream>>>(Wq, WTQ);
    k_transpose<<<dim3(32, 32), tb, 0, stream>>>(Wk, WTK);
    k_transpose<<<dim3(32, 32), tb, 0, stream>>>(Wv, WTV);
    k_transpose<<<dim3(32, 32), tb, 0, stream>>>(Wo, WTO);

    dim3 pg(64, 8);
    k_proj<<<pg, 256, 0, stream>>>(X, WTQ, bq, mask, Q, 0);
    k_proj<<<pg, 256, 0, stream>>>(X, WTK, bk, mask, K, 0);
    k_proj<<<pg, 256, 0, stream>>>(X, WTV, bv, nullptr, V, 0);

    k_landmarks<<<dim3(NLM, BHT), 64, 0, stream>>>(Q, K, QL, KL);

    k_qlk<<<dim3(1, BHT), 256, 0, stream>>>(QL, KL, nullptr, K2, NLM, 0);
    k_qlk<<<dim3(32, BHT), 256, 0, stream>>>(QL, K, mask, SC, LPAD, 1);

    k_v0denom<<<BHT, 128, 0, stream>>>(K2, VA);
    float* cur = VA;
    float* nxt = VB;
    for (int it = 0; it < 6; ++it) {
        k_bmm<<<dim3(2, 2, BHT), 256, 0, stream>>>(K2, cur, KV, P1, NLM, 1.f, 0.f, -1.f, 7.f);
        k_bmm<<<dim3(2, 2, BHT), 256, 0, stream>>>(KV, P1, T3, nullptr, NLM, -1.f, 15.f, 0.f, 0.f);
        k_bmm<<<dim3(2, 2, BHT), 256, 0, stream>>>(KV, T3, P1, nullptr, NLM, -1.f, 13.f, 0.f, 0.f);
        k_bmm<<<dim3(2, 2, BHT), 256, 0, stream>>>(cur, P1, nxt, nullptr, NLM, 0.25f, 0.f, 0.f, 0.f);
        float* t = cur; cur = nxt; nxt = t;
    }

    k_softmax4096<<<BHT * NLM, 256, 0, stream>>>(SC);
    k_k3v_partial<<<dim3(16, BHT), 256, 0, stream>>>(SC, V, PK);
    k_k3v_combine<<<(BHT * NLM * DH) / 256, 256, 0, stream>>>(PK, K3V);
    k_bmm<<<dim3(1, 2, BHT), 256, 0, stream>>>(cur, K3V, MM, nullptr, DH, 1.f, 0.f, 0.f, 0.f);

    k_attn<<<dim3(32, BHT), 256, 0, stream>>>(Q, KL, MM, ATTN);
    k_proj<<<pg, 256, 0, stream>>>(ATTN, WTO, bo, nullptr, out, 1);
}

// Round 3
// 802.143 us; speedup vs baseline: 1.7621x; 1.7621x over previous
//
#include <hip/hip_runtime.h>
#include <hip/hip_bf16.h>
#include <math.h>

#define S_ORIG 4095
#define LPAD   4096
#define NHEADS 16
#define DH     64
#define NLM    128
#define BHT    32        // B * NHEADS
#define HIDDEN 1024
#define QKSCALE 0.35355339059327373f   // 1 / 64^0.25

typedef unsigned short u16;
typedef short s16x8 __attribute__((ext_vector_type(8)));
typedef float f32x4 __attribute__((ext_vector_type(4)));

// ---------------------------------------------------------------------------
// fp32 -> (hi, lo) bf16 split
// ---------------------------------------------------------------------------
__device__ inline void split2(float x, u16& h, u16& l) {
    __hip_bfloat16 bh = __float2bfloat16(x);
    float fh = __bfloat162float(bh);
    __hip_bfloat16 bl = __float2bfloat16(x - fh);
    h = *(u16*)&bh;
    l = *(u16*)&bl;
}

// X (B,4095,1024) fp32 -> XH, XL (8192,1024) bf16-bits, pad row (l==4095) zero.
__global__ __launch_bounds__(256) void k_split_x(const float* __restrict__ X,
                                                 u16* __restrict__ XH,
                                                 u16* __restrict__ XL) {
    int idx = blockIdx.x * 256 + threadIdx.x;      // one thread = 4 elems
    int gr = idx >> 8;                             // row 0..8191
    int c4 = (idx & 255) * 4;
    int b = gr >> 12, l = gr & (LPAD - 1);
    float4 v = make_float4(0.f, 0.f, 0.f, 0.f);
    if (l < S_ORIG) v = *(const float4*)(X + ((size_t)b * S_ORIG + l) * HIDDEN + c4);
    ushort4 h4, l4;
    split2(v.x, h4.x, l4.x); split2(v.y, h4.y, l4.y);
    split2(v.z, h4.z, l4.z); split2(v.w, h4.w, l4.w);
    size_t o = (size_t)gr * HIDDEN + c4;
    *(ushort4*)(XH + o) = h4;
    *(ushort4*)(XL + o) = l4;
}

// W (1024,1024) fp32 -> WH, WL bf16-bits (native [n][k] layout).
__global__ __launch_bounds__(256) void k_split_w(const float* __restrict__ W,
                                                 u16* __restrict__ WH,
                                                 u16* __restrict__ WL) {
    int idx = blockIdx.x * 256 + threadIdx.x;
    size_t o = (size_t)idx * 4;
    float4 v = *(const float4*)(W + o);
    ushort4 h4, l4;
    split2(v.x, h4.x, l4.x); split2(v.y, h4.y, l4.y);
    split2(v.z, h4.z, l4.z); split2(v.w, h4.w, l4.w);
    *(ushort4*)(WH + o) = h4;
    *(ushort4*)(WL + o) = l4;
}

// ---------------------------------------------------------------------------
// Split-bf16 MFMA GEMM:  C = A @ B^T + bias, A 8192x1024 (hi/lo), B 1024x1024
// [n][k] (hi/lo). Logical K = 3072: seg0 = AH*BH, seg1 = AH*BL, seg2 = AL*BH.
// 128x128 tile, BK=32, 256 threads (4 waves), 4x4 16x16x32 fragments/wave.
// mode 0: out[b][h][l][d] (+ optional mask*QKSCALE);  mode 1: out rows l<4095.
// ---------------------------------------------------------------------------
__global__ __launch_bounds__(256) void k_gemm_bf16(
    const u16* __restrict__ AH, const u16* __restrict__ AL,
    const u16* __restrict__ BH, const u16* __restrict__ BL,
    const float* __restrict__ bias, const float* __restrict__ mask,
    float* __restrict__ out, int mode)
{
    __shared__ u16 Alds[128 * 32];
    __shared__ u16 Blds[128 * 32];
    int tid = threadIdx.x;
    int row0 = blockIdx.x * 128, col0 = blockIdx.y * 128;
    int lane = tid & 63, wv = tid >> 6;
    int wr = (wv >> 1) * 64, wc = (wv & 1) * 64;
    int lr = lane & 15, lk = lane >> 4;
    int sr = tid >> 2, sseg = (tid & 3) * 8;       // staging row / k-elem offset

    f32x4 acc[4][4] = {};

    for (int kt = 0; kt < 3072; kt += 32) {
        int s = kt >> 10;
        const u16* Asrc = (s < 2) ? AH : AL;
        const u16* Bsrc = (s == 1) ? BL : BH;
        int ka = kt & 1023;
        #pragma unroll
        for (int h = 0; h < 2; ++h) {
            int r = sr + h * 64;
            __builtin_amdgcn_global_load_lds(
                (const __attribute__((address_space(1))) void*)(Asrc + (size_t)(row0 + r) * HIDDEN + ka + sseg),
                (__attribute__((address_space(3))) void*)(&Alds[r * 32 + sseg]), 16, 0, 0);
            __builtin_amdgcn_global_load_lds(
                (const __attribute__((address_space(1))) void*)(Bsrc + (size_t)(col0 + r) * HIDDEN + ka + sseg),
                (__attribute__((address_space(3))) void*)(&Blds[r * 32 + sseg]), 16, 0, 0);
        }
        __syncthreads();
        s16x8 a[4], b[4];
        #pragma unroll
        for (int i = 0; i < 4; ++i) {
            a[i] = *(const s16x8*)&Alds[(wr + i * 16 + lr) * 32 + lk * 8];
            b[i] = *(const s16x8*)&Blds[(wc + i * 16 + lr) * 32 + lk * 8];
        }
        #pragma unroll
        for (int i = 0; i < 4; ++i)
            #pragma unroll
            for (int j = 0; j < 4; ++j)
                acc[i][j] = __builtin_amdgcn_mfma_f32_16x16x32_bf16(a[i], b[j], acc[i][j], 0, 0, 0);
        __syncthreads();
    }

    #pragma unroll
    for (int i = 0; i < 4; ++i) {
        #pragma unroll
        for (int j = 0; j < 4; ++j) {
            int cc = col0 + wc + j * 16 + lr;
            float bval = bias[cc];
            #pragma unroll
            for (int q = 0; q < 4; ++q) {
                int rr = row0 + wr + i * 16 + lk * 4 + q;
                int bb = rr >> 12, l = rr & (LPAD - 1);
                float val = acc[i][j][q] + bval;
                if (mode == 0) {
                    if (mask) val *= mask[(size_t)bb * LPAD + l] * QKSCALE;
                    out[(((size_t)bb * NHEADS + (cc >> 6)) * LPAD + l) * DH + (cc & 63)] = val;
                } else {
                    if (l < S_ORIG)
                        out[((size_t)bb * S_ORIG + l) * HIDDEN + cc] = val;
                }
            }
        }
    }
}

// ---------------------------------------------------------------------------
// Landmarks: mean over 32 consecutive rows of Q and K. grid (128, 32), 64 thr.
// ---------------------------------------------------------------------------
__global__ void k_landmarks(const float* __restrict__ Q, const float* __restrict__ K,
                            float* __restrict__ QL, float* __restrict__ KL) {
    int n = blockIdx.x, bh = blockIdx.y, d = threadIdx.x;
    size_t base = ((size_t)bh * LPAD + n * 32) * DH + d;
    float sq = 0.f, sk = 0.f;
    #pragma unroll
    for (int s = 0; s < 32; ++s) {
        sq += Q[base + (size_t)s * DH];
        sk += K[base + (size_t)s * DH];
    }
    QL[((size_t)bh * NLM + n) * DH + d] = sq * (1.f / 32.f);
    KL[((size_t)bh * NLM + n) * DH + d] = sk * (1.f / 32.f);
}

// ---------------------------------------------------------------------------
// S = QL @ B^T  (128 x 128, inner 64).
// mode 0: B = KL (128 rows), row-softmax, out K2 (ld 128).
// mode 1: B = K tile (128 rows at n0), out raw scores - 1e9*(1-mask) (ld 4096).
// ---------------------------------------------------------------------------
__global__ __launch_bounds__(256) void k_qlk(const float* __restrict__ QLb,
                                             const float* __restrict__ Bsrc,
                                             const float* __restrict__ mask,
                                             float* __restrict__ out,
                                             int ld_out, int mode) {
    __shared__ float Qt[64][132];
    __shared__ float Bt[64][132];
    int tid = threadIdx.x;
    int tx = tid & 15, ty = tid >> 4;
    int bh = blockIdx.y;
    int n0 = blockIdx.x * 128;
    const float* QLp = QLb + (size_t)bh * NLM * DH;
    const float* Bp = Bsrc + ((mode == 0) ? (size_t)bh * NLM * DH
                                          : (size_t)bh * LPAD * DH + (size_t)n0 * DH);

    #pragma unroll
    for (int q = 0; q < 8; ++q) {
        int idx = tid + q * 256;
        int r = idx >> 4, d4 = idx & 15;
        float4 v = *(const float4*)(QLp + (size_t)r * DH + d4 * 4);
        Qt[d4 * 4 + 0][r] = v.x; Qt[d4 * 4 + 1][r] = v.y;
        Qt[d4 * 4 + 2][r] = v.z; Qt[d4 * 4 + 3][r] = v.w;
        float4 w = *(const float4*)(Bp + (size_t)r * DH + d4 * 4);
        Bt[d4 * 4 + 0][r] = w.x; Bt[d4 * 4 + 1][r] = w.y;
        Bt[d4 * 4 + 2][r] = w.z; Bt[d4 * 4 + 3][r] = w.w;
    }
    __syncthreads();

    float acc[8][8];
    #pragma unroll
    for (int i = 0; i < 8; ++i)
        #pragma unroll
        for (int j = 0; j < 8; ++j) acc[i][j] = 0.f;

    #pragma unroll
    for (int k = 0; k < 64; ++k) {
        float av[8], bv[8];
        float4 t0 = *(const float4*)&Qt[k][ty * 4];
        float4 t1 = *(const float4*)&Qt[k][64 + ty * 4];
        float4 t2 = *(const float4*)&Bt[k][tx * 4];
        float4 t3 = *(const float4*)&Bt[k][64 + tx * 4];
        av[0]=t0.x; av[1]=t0.y; av[2]=t0.z; av[3]=t0.w;
        av[4]=t1.x; av[5]=t1.y; av[6]=t1.z; av[7]=t1.w;
        bv[0]=t2.x; bv[1]=t2.y; bv[2]=t2.z; bv[3]=t2.w;
        bv[4]=t3.x; bv[5]=t3.y; bv[6]=t3.z; bv[7]=t3.w;
        #pragma unroll
        for (int i = 0; i < 8; ++i)
            #pragma unroll
            for (int j = 0; j < 8; ++j)
                acc[i][j] = fmaf(av[i], bv[j], acc[i][j]);
    }

    if (mode == 1) {
        int b = bh >> 4;
        #pragma unroll
        for (int i = 0; i < 8; ++i) {
            int r = (i >> 2) * 64 + ty * 4 + (i & 3);
            #pragma unroll
            for (int jh = 0; jh < 2; ++jh) {
                int c = n0 + jh * 64 + tx * 4;
                float4 m4 = *(const float4*)(mask + (size_t)b * LPAD + c);
                float4 res;
                res.x = acc[i][jh * 4 + 0] - 1e9f * (1.f - m4.x);
                res.y = acc[i][jh * 4 + 1] - 1e9f * (1.f - m4.y);
                res.z = acc[i][jh * 4 + 2] - 1e9f * (1.f - m4.z);
                res.w = acc[i][jh * 4 + 3] - 1e9f * (1.f - m4.w);
                *(float4*)(out + ((size_t)bh * NLM + r) * ld_out + c) = res;
            }
        }
    } else {
        float m[8], s[8];
        #pragma unroll
        for (int i = 0; i < 8; ++i) {
            m[i] = acc[i][0];
            #pragma unroll
            for (int j = 1; j < 8; ++j) m[i] = fmaxf(m[i], acc[i][j]);
        }
        #pragma unroll
        for (int o = 8; o >= 1; o >>= 1)
            #pragma unroll
            for (int i = 0; i < 8; ++i) m[i] = fmaxf(m[i], __shfl_xor(m[i], o));
        #pragma unroll
        for (int i = 0; i < 8; ++i) {
            s[i] = 0.f;
            #pragma unroll
            for (int j = 0; j < 8; ++j) {
                acc[i][j] = expf(acc[i][j] - m[i]);
                s[i] += acc[i][j];
            }
        }
        #pragma unroll
        for (int o = 8; o >= 1; o >>= 1)
            #pragma unroll
            for (int i = 0; i < 8; ++i) s[i] += __shfl_xor(s[i], o);
        #pragma unroll
        for (int i = 0; i < 8; ++i) {
            int r = (i >> 2) * 64 + ty * 4 + (i & 3);
            float inv = 1.f / s[i];
            #pragma unroll
            for (int jh = 0; jh < 2; ++jh) {
                int c = jh * 64 + tx * 4;
                float4 res;
                res.x = acc[i][jh * 4 + 0] * inv;
                res.y = acc[i][jh * 4 + 1] * inv;
                res.z = acc[i][jh * 4 + 2] * inv;
                res.w = acc[i][jh * 4 + 3] * inv;
                *(float4*)(out + ((size_t)bh * NLM + r) * ld_out + c) = res;
            }
        }
    }
}

// ---------------------------------------------------------------------------
// denom + V0 = K2^T / denom. grid 32, 128 threads.
// ---------------------------------------------------------------------------
__global__ void k_v0denom(const float* __restrict__ K2b, float* __restrict__ V0b) {
    int bh = blockIdx.x, t = threadIdx.x;
    const float* K2 = K2b + (size_t)bh * NLM * NLM;
    float* V0 = V0b + (size_t)bh * NLM * NLM;
    float cs = 0.f, rs = 0.f;
    for (int r = 0; r < NLM; ++r) cs += fabsf(K2[r * NLM + t]);
    for (int c = 0; c < NLM; ++c) rs += fabsf(K2[t * NLM + c]);
    __shared__ float sc[128], sr[128];
    sc[t] = cs; sr[t] = rs;
    __syncthreads();
    for (int s = 64; s > 0; s >>= 1) {
        if (t < s) {
            sc[t] = fmaxf(sc[t], sc[t + s]);
            sr[t] = fmaxf(sr[t], sr[t + s]);
        }
        __syncthreads();
    }
    float invden = 1.f / (sc[0] * sr[0]);
    for (int idx = t; idx < NLM * NLM; idx += 128) {
        int i = idx >> 7, j = idx & 127;
        V0[idx] = K2[j * NLM + i] * invden;
    }
}

// ---------------------------------------------------------------------------
// Batched matmul: C = alpha*(A@B) + sI  (A 128x128, B 128xN).
// Optional second output C2 = alpha2*(A@B) + s2I.
// grid (N/64, 2, 32), 256 threads, 4x4 per thread, full K=128 staged.
// ---------------------------------------------------------------------------
__global__ __launch_bounds__(256) void k_bmm(const float* __restrict__ Ab,
                                             const float* __restrict__ Bb,
                                             float* __restrict__ Cb,
                                             float* __restrict__ C2b,
                                             int N, float alpha, float sI,
                                             float alpha2, float sI2) {
    __shared__ float At[128][68];
    __shared__ float Bs[128][68];
    int tid = threadIdx.x;
    int tx = tid & 15, ty = tid >> 4;
    int bh = blockIdx.z;
    int r0 = blockIdx.y * 64, c0 = blockIdx.x * 64;
    const float* A = Ab + (size_t)bh * NLM * NLM;
    const float* Bm = Bb + (size_t)bh * NLM * N;

    #pragma unroll
    for (int q = 0; q < 8; ++q) {
        int idx = tid + q * 256;
        int r = idx >> 5, k4 = idx & 31;
        float4 v = *(const float4*)(A + (size_t)(r0 + r) * NLM + k4 * 4);
        At[k4 * 4 + 0][r] = v.x; At[k4 * 4 + 1][r] = v.y;
        At[k4 * 4 + 2][r] = v.z; At[k4 * 4 + 3][r] = v.w;
        int bk = idx >> 4, c4 = idx & 15;
        float4 w = *(const float4*)(Bm + (size_t)bk * N + c0 + c4 * 4);
        *(float4*)&Bs[bk][c4 * 4] = w;
    }
    __syncthreads();

    float acc[4][4];
    #pragma unroll
    for (int i = 0; i < 4; ++i)
        #pragma unroll
        for (int j = 0; j < 4; ++j) acc[i][j] = 0.f;

    #pragma unroll 4
    for (int k = 0; k < 128; ++k) {
        float4 a = *(const float4*)&At[k][ty * 4];
        float4 b = *(const float4*)&Bs[k][tx * 4];
        float av[4] = {a.x, a.y, a.z, a.w};
        float bv[4] = {b.x, b.y, b.z, b.w};
        #pragma unroll
        for (int i = 0; i < 4; ++i)
            #pragma unroll
            for (int j = 0; j < 4; ++j)
                acc[i][j] = fmaf(av[i], bv[j], acc[i][j]);
    }

    float* C = Cb + (size_t)bh * NLM * N;
    float* C2 = C2b ? (C2b + (size_t)bh * NLM * N) : nullptr;
    #pragma unroll
    for (int i = 0; i < 4; ++i) {
        int gr = r0 + ty * 4 + i;
        int gc0 = c0 + tx * 4;
        float4 res, res2;
        float* rp = &res.x; float* rp2 = &res2.x;
        #pragma unroll
        for (int j = 0; j < 4; ++j) {
            float idadd = (gr == gc0 + j) ? 1.f : 0.f;
            rp[j] = alpha * acc[i][j] + sI * idadd;
            rp2[j] = alpha2 * acc[i][j] + sI2 * idadd;
        }
        *(float4*)(C + (size_t)gr * N + gc0) = res;
        if (C2) *(float4*)(C2 + (size_t)gr * N + gc0) = res2;
    }
}

// ---------------------------------------------------------------------------
// Row softmax over 4096-long rows of SC (in place). grid 4096, 256 threads.
// ---------------------------------------------------------------------------
__global__ __launch_bounds__(256) void k_softmax4096(float* __restrict__ SC) {
    float* p = SC + (size_t)blockIdx.x * LPAD;
    int tid = threadIdx.x;
    float4 v[4];
    #pragma unroll
    for (int q = 0; q < 4; ++q) v[q] = *(float4*)(p + tid * 16 + q * 4);

    float m = -1e30f;
    #pragma unroll
    for (int q = 0; q < 4; ++q) {
        m = fmaxf(m, fmaxf(fmaxf(v[q].x, v[q].y), fmaxf(v[q].z, v[q].w)));
    }
    __shared__ float red[4], red2[4];
    for (int o = 32; o >= 1; o >>= 1) m = fmaxf(m, __shfl_xor(m, o));
    int wid = tid >> 6;
    if ((tid & 63) == 0) red[wid] = m;
    __syncthreads();
    m = fmaxf(fmaxf(red[0], red[1]), fmaxf(red[2], red[3]));

    float s = 0.f;
    #pragma unroll
    for (int q = 0; q < 4; ++q) {
        v[q].x = expf(v[q].x - m); v[q].y = expf(v[q].y - m);
        v[q].z = expf(v[q].z - m); v[q].w = expf(v[q].w - m);
        s += v[q].x + v[q].y + v[q].z + v[q].w;
    }
    for (int o = 32; o >= 1; o >>= 1) s += __shfl_xor(s, o);
    if ((tid & 63) == 0) red2[wid] = s;
    __syncthreads();
    s = red2[0] + red2[1] + red2[2] + red2[3];
    float inv = 1.f / s;
    #pragma unroll
    for (int q = 0; q < 4; ++q) {
        v[q].x *= inv; v[q].y *= inv; v[q].z *= inv; v[q].w *= inv;
        *(float4*)(p + tid * 16 + q * 4) = v[q];
    }
}

// ---------------------------------------------------------------------------
// Partial kernel_3 @ V over a 256-wide n chunk. grid (16, 32), 256 threads.
// ---------------------------------------------------------------------------
__global__ __launch_bounds__(256) void k_k3v_partial(const float* __restrict__ SC,
                                                     const float* __restrict__ V,
                                                     float* __restrict__ P) {
    __shared__ float Pt[64][132];
    __shared__ float Vs[64][68];
    int tid = threadIdx.x;
    int tx = tid & 7, ty = tid >> 3;
    int sp = blockIdx.x, bh = blockIdx.y;
    int n0 = sp * 256;

    float acc[4][8];
    #pragma unroll
    for (int i = 0; i < 4; ++i)
        #pragma unroll
        for (int j = 0; j < 8; ++j) acc[i][j] = 0.f;

    for (int ns = 0; ns < 4; ++ns) {
        int nb = n0 + ns * 64;
        #pragma unroll
        for (int q = 0; q < 8; ++q) {
            int idx = tid + q * 256;
            int r = idx >> 4, n4 = idx & 15;
            float4 v = *(const float4*)(SC + ((size_t)bh * NLM + r) * LPAD + nb + n4 * 4);
            Pt[n4 * 4 + 0][r] = v.x; Pt[n4 * 4 + 1][r] = v.y;
            Pt[n4 * 4 + 2][r] = v.z; Pt[n4 * 4 + 3][r] = v.w;
        }
        #pragma unroll
        for (int q = 0; q < 4; ++q) {
            int idx = tid + q * 256;
            int vr = idx >> 4, d4 = idx & 15;
            float4 w = *(const float4*)(V + ((size_t)bh * LPAD + nb + vr) * DH + d4 * 4);
            *(float4*)&Vs[vr][d4 * 4] = w;
        }
        __syncthreads();
        #pragma unroll 4
        for (int nn = 0; nn < 64; ++nn) {
            float4 a4 = *(const float4*)&Pt[nn][ty * 4];
            float4 b0 = *(const float4*)&Vs[nn][tx * 8];
            float4 b1 = *(const float4*)&Vs[nn][tx * 8 + 4];
            float a[4] = {a4.x, a4.y, a4.z, a4.w};
            float b[8] = {b0.x, b0.y, b0.z, b0.w, b1.x, b1.y, b1.z, b1.w};
            #pragma unroll
            for (int i = 0; i < 4; ++i)
                #pragma unroll
                for (int j = 0; j < 8; ++j)
                    acc[i][j] = fmaf(a[i], b[j], acc[i][j]);
        }
        __syncthreads();
    }
    #pragma unroll
    for (int i = 0; i < 4; ++i) {
        int r = ty * 4 + i, d = tx * 8;
        *(float4*)(P + (((size_t)bh * 16 + sp) * NLM + r) * DH + d) =
            make_float4(acc[i][0], acc[i][1], acc[i][2], acc[i][3]);
        *(float4*)(P + (((size_t)bh * 16 + sp) * NLM + r) * DH + d + 4) =
            make_float4(acc[i][4], acc[i][5], acc[i][6], acc[i][7]);
    }
}

__global__ void k_k3v_combine(const float* __restrict__ P, float* __restrict__ O) {
    int idx = blockIdx.x * 256 + threadIdx.x;
    int bh = idx >> 13, rem = idx & 8191;
    float s = 0.f;
    for (int sp = 0; sp < 16; ++sp)
        s += P[((size_t)bh * 16 + sp) * 8192 + rem];
    O[idx] = s;
}

// ---------------------------------------------------------------------------
// kernel_1 stage fused: softmax(Q_tile @ KL^T) @ M  -> ATTN hi/lo bf16
// grid (32 l-tiles, 32 bh), 256 threads.
// ---------------------------------------------------------------------------
__global__ __launch_bounds__(256) void k_attn(const float* __restrict__ Q,
                                              const float* __restrict__ KLb,
                                              const float* __restrict__ MMb,
                                              u16* __restrict__ ATH,
                                              u16* __restrict__ ATL) {
    __shared__ float buf[2 * 64 * 132];     // Qt(64x132) | KLt(64x132); later P(128x132)
    __shared__ float Ms[128 * 68];
    int tid = threadIdx.x;
    int tx = tid & 15, ty = tid >> 4;
    int l0 = blockIdx.x * 128, bh = blockIdx.y;
    int b = bh >> 4, hh = bh & 15;
    float* Qt = buf;
    float* KLt = buf + 64 * 132;

    #pragma unroll
    for (int q = 0; q < 8; ++q) {
        int idx = tid + q * 256;
        int r = idx >> 4, d4 = idx & 15;
        float4 v = *(const float4*)(Q + ((size_t)bh * LPAD + l0 + r) * DH + d4 * 4);
        Qt[(d4 * 4 + 0) * 132 + r] = v.x; Qt[(d4 * 4 + 1) * 132 + r] = v.y;
        Qt[(d4 * 4 + 2) * 132 + r] = v.z; Qt[(d4 * 4 + 3) * 132 + r] = v.w;
        float4 w = *(const float4*)(KLb + ((size_t)bh * NLM + r) * DH + d4 * 4);
        KLt[(d4 * 4 + 0) * 132 + r] = w.x; KLt[(d4 * 4 + 1) * 132 + r] = w.y;
        KLt[(d4 * 4 + 2) * 132 + r] = w.z; KLt[(d4 * 4 + 3) * 132 + r] = w.w;
        float4 u = *(const float4*)(MMb + ((size_t)bh * NLM + r) * DH + d4 * 4);
        *(float4*)&Ms[r * 68 + d4 * 4] = u;
    }
    __syncthreads();

    float acc[8][8];
    #pragma unroll
    for (int i = 0; i < 8; ++i)
        #pragma unroll
        for (int j = 0; j < 8; ++j) acc[i][j] = 0.f;

    #pragma unroll
    for (int k = 0; k < 64; ++k) {
        float av[8], bv[8];
        float4 t0 = *(const float4*)&Qt[k * 132 + ty * 4];
        float4 t1 = *(const float4*)&Qt[k * 132 + 64 + ty * 4];
        float4 t2 = *(const float4*)&KLt[k * 132 + tx * 4];
        float4 t3 = *(const float4*)&KLt[k * 132 + 64 + tx * 4];
        av[0]=t0.x; av[1]=t0.y; av[2]=t0.z; av[3]=t0.w;
        av[4]=t1.x; av[5]=t1.y; av[6]=t1.z; av[7]=t1.w;
        bv[0]=t2.x; bv[1]=t2.y; bv[2]=t2.z; bv[3]=t2.w;
        bv[4]=t3.x; bv[5]=t3.y; bv[6]=t3.z; bv[7]=t3.w;
        #pragma unroll
        for (int i = 0; i < 8; ++i)
            #pragma unroll
            for (int j = 0; j < 8; ++j)
                acc[i][j] = fmaf(av[i], bv[j], acc[i][j]);
    }

    // row softmax over 128 cols
    float m[8], s[8];
    #pragma unroll
    for (int i = 0; i < 8; ++i) {
        m[i] = acc[i][0];
        #pragma unroll
        for (int j = 1; j < 8; ++j) m[i] = fmaxf(m[i], acc[i][j]);
    }
    #pragma unroll
    for (int o = 8; o >= 1; o >>= 1)
        #pragma unroll
        for (int i = 0; i < 8; ++i) m[i] = fmaxf(m[i], __shfl_xor(m[i], o));
    #pragma unroll
    for (int i = 0; i < 8; ++i) {
        s[i] = 0.f;
        #pragma unroll
        for (int j = 0; j < 8; ++j) {
            acc[i][j] = expf(acc[i][j] - m[i]);
            s[i] += acc[i][j];
        }
    }
    #pragma unroll
    for (int o = 8; o >= 1; o >>= 1)
        #pragma unroll
        for (int i = 0; i < 8; ++i) s[i] += __shfl_xor(s[i], o);

    __syncthreads();   // all Qt/KLt reads done; safe to overwrite with P
    #pragma unroll
    for (int i = 0; i < 8; ++i) {
        int r = (i >> 2) * 64 + ty * 4 + (i & 3);
        float inv = 1.f / s[i];
        #pragma unroll
        for (int j = 0; j < 8; ++j) {
            int c = (j >> 2) * 64 + tx * 4 + (j & 3);
            buf[r * 132 + c] = acc[i][j] * inv;
        }
    }
    __syncthreads();

    // out = P @ Ms : each thread 8 rows x 4 cols (d = tx*4..)
    float o2[8][4];
    #pragma unroll
    for (int i = 0; i < 8; ++i)
        #pragma unroll
        for (int j = 0; j < 4; ++j) o2[i][j] = 0.f;
    #pragma unroll 4
    for (int n = 0; n < 128; ++n) {
        float4 b4 = *(const float4*)&Ms[n * 68 + tx * 4];
        float bv[4] = {b4.x, b4.y, b4.z, b4.w};
        #pragma unroll
        for (int i = 0; i < 8; ++i) {
            int r = (i >> 2) * 64 + ty * 4 + (i & 3);
            float a = buf[r * 132 + n];
            #pragma unroll
            for (int j = 0; j < 4; ++j)
                o2[i][j] = fmaf(a, bv[j], o2[i][j]);
        }
    }
    #pragma unroll
    for (int i = 0; i < 8; ++i) {
        int l = l0 + (i >> 2) * 64 + ty * 4 + (i & 3);
        size_t base = ((size_t)b * LPAD + l) * HIDDEN + hh * DH + tx * 4;
        ushort4 h4, l4;
        split2(o2[i][0], h4.x, l4.x); split2(o2[i][1], h4.y, l4.y);
        split2(o2[i][2], h4.z, l4.z); split2(o2[i][3], h4.w, l4.w);
        *(ushort4*)(ATH + base) = h4;
        *(ushort4*)(ATL + base) = l4;
    }
}

// ---------------------------------------------------------------------------
extern "C" void kernel_launch(void* const* d_in, const int* in_sizes, int n_in,
                              void* d_out, int out_size, void* d_ws, size_t ws_size,
                              hipStream_t stream) {
    (void)in_sizes; (void)n_in; (void)out_size; (void)ws_size;
    const float* X    = (const float*)d_in[0];
    const float* mask = (const float*)d_in[1];
    const float* Wq   = (const float*)d_in[2];
    const float* bq   = (const float*)d_in[3];
    const float* Wk   = (const float*)d_in[4];
    const float* bk   = (const float*)d_in[5];
    const float* Wv   = (const float*)d_in[6];
    const float* bv   = (const float*)d_in[7];
    const float* Wo   = (const float*)d_in[8];
    const float* bo   = (const float*)d_in[9];
    float* out = (float*)d_out;
    float* w = (float*)d_ws;

    size_t o = 0;
    u16* WQH = (u16*)(w + o); o += (size_t)HIDDEN * HIDDEN / 2;
    u16* WQL = (u16*)(w + o); o += (size_t)HIDDEN * HIDDEN / 2;
    u16* WKH = (u16*)(w + o); o += (size_t)HIDDEN * HIDDEN / 2;
    u16* WKL = (u16*)(w + o); o += (size_t)HIDDEN * HIDDEN / 2;
    u16* WVH = (u16*)(w + o); o += (size_t)HIDDEN * HIDDEN / 2;
    u16* WVL = (u16*)(w + o); o += (size_t)HIDDEN * HIDDEN / 2;
    u16* WOH = (u16*)(w + o); o += (size_t)HIDDEN * HIDDEN / 2;
    u16* WOL = (u16*)(w + o); o += (size_t)HIDDEN * HIDDEN / 2;
    float* Q   = w + o; o += (size_t)BHT * LPAD * DH;
    float* K   = w + o; o += (size_t)BHT * LPAD * DH;
    float* V   = w + o; o += (size_t)BHT * LPAD * DH;
    float* QL  = w + o; o += (size_t)BHT * NLM * DH;
    float* KL  = w + o; o += (size_t)BHT * NLM * DH;
    float* K2  = w + o; o += (size_t)BHT * NLM * NLM;
    float* VA  = w + o; o += (size_t)BHT * NLM * NLM;
    float* VB  = w + o; o += (size_t)BHT * NLM * NLM;
    float* KV  = w + o; o += (size_t)BHT * NLM * NLM;
    float* P1  = w + o; o += (size_t)BHT * NLM * NLM;
    float* T3  = w + o; o += (size_t)BHT * NLM * NLM;
    float* PK  = w + o; o += (size_t)BHT * 16 * NLM * DH;
    float* K3V = w + o; o += (size_t)BHT * NLM * DH;
    float* MM  = w + o; o += (size_t)BHT * NLM * DH;
    float* SC  = w + o; o += (size_t)BHT * NLM * LPAD;

    // Time-shared aliases of the SC region (all dead/live windows disjoint):
    //   phase 1: XH/XL (consumed by the 3 QKV GEMMs, before SC is written)
    //   phase 2: SC scores (written by k_qlk mode 1)
    //   phase 3: ATH/ATL (written by k_attn after SC is fully consumed)
    u16* XH  = (u16*)SC;
    u16* XL  = XH + (size_t)2 * LPAD * HIDDEN;
    u16* ATH = (u16*)SC;
    u16* ATL = ATH + (size_t)2 * LPAD * HIDDEN;

    k_split_x<<<8192, 256, 0, stream>>>(X, XH, XL);
    k_split_w<<<1024, 256, 0, stream>>>(Wq, WQH, WQL);
    k_split_w<<<1024, 256, 0, stream>>>(Wk, WKH, WKL);
    k_split_w<<<1024, 256, 0, stream>>>(Wv, WVH, WVL);
    k_split_w<<<1024, 256, 0, stream>>>(Wo, WOH, WOL);

    dim3 gg(64, 8);
    k_gemm_bf16<<<gg, 256, 0, stream>>>(XH, XL, WQH, WQL, bq, mask, Q, 0);
    k_gemm_bf16<<<gg, 256, 0, stream>>>(XH, XL, WKH, WKL, bk, mask, K, 0);
    k_gemm_bf16<<<gg, 256, 0, stream>>>(XH, XL, WVH, WVL, bv, nullptr, V, 0);

    k_landmarks<<<dim3(NLM, BHT), 64, 0, stream>>>(Q, K, QL, KL);

    k_qlk<<<dim3(1, BHT), 256, 0, stream>>>(QL, KL, nullptr, K2, NLM, 0);
    k_qlk<<<dim3(32, BHT), 256, 0, stream>>>(QL, K, mask, SC, LPAD, 1);

    k_v0denom<<<BHT, 128, 0, stream>>>(K2, VA);
    float* cur = VA;
    float* nxt = VB;
    for (int it = 0; it < 6; ++it) {
        k_bmm<<<dim3(2, 2, BHT), 256, 0, stream>>>(K2, cur, KV, P1, NLM, 1.f, 0.f, -1.f, 7.f);
        k_bmm<<<dim3(2, 2, BHT), 256, 0, stream>>>(KV, P1, T3, nullptr, NLM, -1.f, 15.f, 0.f, 0.f);
        k_bmm<<<dim3(2, 2, BHT), 256, 0, stream>>>(KV, T3, P1, nullptr, NLM, -1.f, 13.f, 0.f, 0.f);
        k_bmm<<<dim3(2, 2, BHT), 256, 0, stream>>>(cur, P1, nxt, nullptr, NLM, 0.25f, 0.f, 0.f, 0.f);
        float* t = cur; cur = nxt; nxt = t;
    }

    k_softmax4096<<<BHT * NLM, 256, 0, stream>>>(SC);
    k_k3v_partial<<<dim3(16, BHT), 256, 0, stream>>>(SC, V, PK);
    k_k3v_combine<<<(BHT * NLM * DH) / 256, 256, 0, stream>>>(PK, K3V);
    k_bmm<<<dim3(1, 2, BHT), 256, 0, stream>>>(cur, K3V, MM, nullptr, DH, 1.f, 0.f, 0.f, 0.f);

    k_attn<<<dim3(32, BHT), 256, 0, stream>>>(Q, KL, MM, ATH, ATL);
    k_gemm_bf16<<<gg, 256, 0, stream>>>(ATH, ATL, WOH, WOL, bo, nullptr, out, 1);
}